// Round 4
// baseline (4688.398 us; speedup 1.0000x reference)
//
#include <hip/hip_runtime.h>
#include <math.h>

#define DEVI __device__ __forceinline__

namespace {

constexpr int NPAIR = 160;          // kept frame pairs
constexpr int CF    = 256;          // feature channels
constexpr int HFc   = 24, WFc = 42, HW = HFc * WFc;
constexpr int INSZ  = 1030;
constexpr int KDEC  = 1286;

DEVI float sigm(float x) { return 1.f / (1.f + expf(-x)); }
DEVI float lrelu(float v) { return v > 0.f ? v : 0.1f * v; }

// ---------------------------------------------------------------------------
// Correlation: corr[kk][dy*9+dx][h][w] = lrelu((1/256) * sum_c f1[c,h,w]*f2[c,h+dy-4,w+dx-4])
// kk is chunk-local; global pair = k0 + kk. block: (kk, 4-row h tile).
// thread: (hh in 4, dy in 9, seg in 7), 6 w-positions each.
// ---------------------------------------------------------------------------
__global__ __launch_bounds__(256) void corr_kernel(const float* __restrict__ feat,
                                                   float* __restrict__ out, int k0) {
  int kk = blockIdx.x;
  int k  = k0 + kk;
  int h0 = blockIdx.y * 4;
  int g  = k + k / 10;                       // global pair index (skip track boundaries)
  const float* f1 = feat + (size_t)g * CF * HW;
  const float* f2 = feat + (size_t)(g + 1) * CF * HW;

  __shared__ float s1[8 * 4 * 42];           // [c][hh][x]
  __shared__ float s2[8 * 12 * 50];          // [c][r](y=h0+r-4)[xx](x=xx-4)

  int tid = threadIdx.x;
  int hh = tid / 63, rem = tid % 63, dy = rem / 7, seg = rem % 7;
  bool active = tid < 252;

  float acc[9][6];
#pragma unroll
  for (int i = 0; i < 9; i++)
#pragma unroll
    for (int j = 0; j < 6; j++) acc[i][j] = 0.f;

  for (int c0 = 0; c0 < CF; c0 += 8) {
    __syncthreads();
    for (int idx = tid; idx < 8 * 4 * 42; idx += 256) {
      int c = idx / 168, r2 = idx % 168, yy = r2 / 42, x = r2 % 42;
      s1[idx] = f1[(size_t)(c0 + c) * HW + (h0 + yy) * WFc + x];
    }
    for (int idx = tid; idx < 8 * 12 * 50; idx += 256) {
      int c = idx / 600, r2 = idx % 600, r = r2 / 50, xx = r2 % 50;
      int y = h0 + r - 4, x = xx - 4;
      float v = 0.f;
      if (y >= 0 && y < HFc && x >= 0 && x < WFc)
        v = f2[(size_t)(c0 + c) * HW + y * WFc + x];
      s2[idx] = v;
    }
    __syncthreads();
    if (active) {
#pragma unroll
      for (int c = 0; c < 8; c++) {
        float f1v[6];
        const float* p1 = &s1[(c * 4 + hh) * 42 + seg * 6];
#pragma unroll
        for (int i = 0; i < 6; i++) f1v[i] = p1[i];
        float f2v[14];
        const float* p2 = &s2[(c * 12 + hh + dy) * 50 + seg * 6];
#pragma unroll
        for (int i = 0; i < 14; i++) f2v[i] = p2[i];
#pragma unroll
        for (int dx = 0; dx < 9; dx++)
#pragma unroll
          for (int w = 0; w < 6; w++) acc[dx][w] = fmaf(f1v[w], f2v[w + dx], acc[dx][w]);
      }
    }
  }
  if (active) {
#pragma unroll
    for (int dx = 0; dx < 9; dx++) {
      int o = dy * 9 + dx;
#pragma unroll
      for (int w = 0; w < 6; w++) {
        float v = lrelu(acc[dx][w] * (1.f / 256.f));
        out[((size_t)kk * 81 + o) * HW + (h0 + hh) * WFc + seg * 6 + w] = v;
      }
    }
  }
}

// ---------------------------------------------------------------------------
// Direct 3x3 conv, pad 1, leaky relu. block: (chunk-local image n, 16-oc tile).
// 256 threads, thread owns 4 flat positions, acc[16 oc][4 pos].
// ---------------------------------------------------------------------------
template <int IC, int OC>
__global__ __launch_bounds__(256) void conv_kernel(const float* __restrict__ in,
                                                   const float* __restrict__ wgt,
                                                   const float* __restrict__ bias,
                                                   float* __restrict__ out) {
  int n  = blockIdx.x;
  int ot = blockIdx.y;                       // oc tile of 16
  __shared__ float sin_[8 * 26 * 44];        // padded spatial, 8-ic chunk
  __shared__ float sw_[8 * 9 * 16];          // [ic][kpos][ocl]
  int tid = threadIdx.x;

  float acc[16][4];
#pragma unroll
  for (int o = 0; o < 16; o++)
#pragma unroll
    for (int i = 0; i < 4; i++) acc[o][i] = 0.f;

  int py[4], px[4];
  bool val[4];
#pragma unroll
  for (int i = 0; i < 4; i++) {
    int p = tid + i * 256;
    val[i] = p < HW;
    if (!val[i]) p = 0;
    py[i] = p / WFc;
    px[i] = p % WFc;
  }

  for (int ic0 = 0; ic0 < IC; ic0 += 8) {
    __syncthreads();
    for (int idx = tid; idx < 8 * 26 * 44; idx += 256) {
      int c = idx / 1144, r2 = idx % 1144, yy = r2 / 44, xx = r2 % 44;
      int iy = yy - 1, ix = xx - 1;
      float v = 0.f;
      if (iy >= 0 && iy < HFc && ix >= 0 && ix < WFc && (ic0 + c) < IC)
        v = in[((size_t)n * IC + ic0 + c) * HW + iy * WFc + ix];
      sin_[idx] = v;
    }
    for (int idx = tid; idx < 8 * 9 * 16; idx += 256) {
      int c = idx / 144, r2 = idx % 144, kp = r2 / 16, ocl = r2 % 16;
      float v = 0.f;
      if (ic0 + c < IC) v = wgt[(((size_t)(ot * 16 + ocl)) * IC + ic0 + c) * 9 + kp];
      sw_[idx] = v;
    }
    __syncthreads();
#pragma unroll
    for (int c = 0; c < 8; c++) {
#pragma unroll
      for (int kp = 0; kp < 9; kp++) {
        int ky = kp / 3, kx = kp % 3;
        float wv[16];
#pragma unroll
        for (int o = 0; o < 16; o++) wv[o] = sw_[(c * 9 + kp) * 16 + o];
        float iv[4];
#pragma unroll
        for (int i = 0; i < 4; i++) iv[i] = sin_[c * 1144 + (py[i] + ky) * 44 + px[i] + kx];
#pragma unroll
        for (int o = 0; o < 16; o++)
#pragma unroll
          for (int i = 0; i < 4; i++) acc[o][i] = fmaf(wv[o], iv[i], acc[o][i]);
      }
    }
  }

#pragma unroll
  for (int o = 0; o < 16; o++) {
    float bb = bias[ot * 16 + o];
#pragma unroll
    for (int i = 0; i < 4; i++) {
      if (val[i]) {
        float v = lrelu(acc[o][i] + bb);
        out[((size_t)n * OC + ot * 16 + o) * HW + tid + i * 256] = v;
      }
    }
  }
}

// ---------------------------------------------------------------------------
// ROI align (torchvision, aligned=False), 4x4 out, 2x2 sampling.
// feat is chunk-local (pair kk); boxes/out use global pair k0+kk.
// out[k][c*16 + py*4 + px]
// ---------------------------------------------------------------------------
DEVI float bilinear(const float* __restrict__ f, float y, float x) {
  bool valid = (y >= -1.f) && (y <= (float)HFc) && (x >= -1.f) && (x <= (float)WFc);
  if (!valid) return 0.f;
  y = fmaxf(y, 0.f);
  x = fmaxf(x, 0.f);
  int y0 = min((int)floorf(y), HFc - 1);
  int x0 = min((int)floorf(x), WFc - 1);
  int y1 = min(y0 + 1, HFc - 1);
  int x1 = min(x0 + 1, WFc - 1);
  if (y0 >= HFc - 1) y = (float)y0;
  if (x0 >= WFc - 1) x = (float)x0;
  float ly = y - y0, lx = x - x0, hy = 1.f - ly, hx = 1.f - lx;
  return hy * hx * f[y0 * WFc + x0] + hy * lx * f[y0 * WFc + x1] +
         ly * hx * f[y1 * WFc + x0] + ly * lx * f[y1 * WFc + x1];
}

__global__ __launch_bounds__(256) void roi_kernel(const float* __restrict__ feat,
                                                  const float* __restrict__ boxes,
                                                  const int* __restrict__ isz,
                                                  float* __restrict__ out, int k0) {
  int kk = blockIdx.x;
  int k  = k0 + kk;
  int g = k + k / 10;
  float scale = 24.0f / (float)isz[0];
  float x1 = boxes[g * 4 + 0] * scale, y1 = boxes[g * 4 + 1] * scale;
  float x2 = boxes[g * 4 + 2] * scale, y2 = boxes[g * 4 + 3] * scale;
  float bw = fmaxf(x2 - x1, 1.0f) * 0.25f;
  float bh = fmaxf(y2 - y1, 1.0f) * 0.25f;
  int tid = threadIdx.x;
  int c = tid % 64, bq = tid / 64;
  const float* f = feat + ((size_t)kk * 64 + c) * HW;
#pragma unroll
  for (int i = 0; i < 4; i++) {
    int bin = bq * 4 + i;
    int pyb = bin / 4, pxb = bin % 4;
    float s = 0.f;
#pragma unroll
    for (int sy = 0; sy < 2; sy++)
#pragma unroll
      for (int sx = 0; sx < 2; sx++) {
        float yy = y1 + (pyb + (sy + 0.5f) * 0.5f) * bh;
        float xx = x1 + (pxb + (sx + 0.5f) * 0.5f) * bw;
        s += bilinear(f, yy, xx);
      }
    out[(size_t)k * 1024 + c * 16 + pyb * 4 + pxb] = s * 0.25f;
  }
}

// ---------------------------------------------------------------------------
// 32x32 LDS-tiled transpose: src[R][C] -> dst[C][R]
// ---------------------------------------------------------------------------
__global__ __launch_bounds__(256) void transpose_kernel(const float* __restrict__ src,
                                                        float* __restrict__ dst, int R, int C) {
  __shared__ float t[32][33];
  int bx = blockIdx.x * 32, by = blockIdx.y * 32;
  int tx = threadIdx.x % 32, ty = threadIdx.x / 32;
  for (int i = 0; i < 32; i += 8) {
    int r = by + ty + i, c = bx + tx;
    t[ty + i][tx] = (r < R && c < C) ? src[(size_t)r * C + c] : 0.f;
  }
  __syncthreads();
  for (int i = 0; i < 32; i += 8) {
    int c = bx + ty + i, r = by + tx;
    if (c < C && r < R) dst[(size_t)c * R + r] = t[tx][ty + i];
  }
}

// ---------------------------------------------------------------------------
// G_x[t][b][oc] = sum_k enc_in[b][t][k] * Wt[k][oc] + bih[oc] + bhh[oc]
// grid (10 t, 4 b-quads, 2 oc halves); thread owns 2 consecutive oc, acc over 4 b.
// ---------------------------------------------------------------------------
__global__ __launch_bounds__(256) void gx_kernel(const float* __restrict__ diffs,
                                                 const float* __restrict__ roi,
                                                 const float* __restrict__ Wt,
                                                 const float* __restrict__ bih,
                                                 const float* __restrict__ bhh,
                                                 float* __restrict__ Gx) {
  int t = blockIdx.x, bq = blockIdx.y, och = blockIdx.z;
  int tid = threadIdx.x;
  int oc = och * 512 + tid * 2;
  __shared__ float xs[4][256];
  float acc[2][4] = {{0.f, 0.f, 0.f, 0.f}, {0.f, 0.f, 0.f, 0.f}};

  for (int k0 = 0; k0 < INSZ; k0 += 256) {
    int kc = min(256, INSZ - k0);
    __syncthreads();
    for (int idx = tid; idx < 4 * 256; idx += 256) {
      int bi = idx / 256, kk = idx % 256;
      float v = 0.f;
      int k = k0 + kk;
      if (kk < kc) {
        int b = bq * 4 + bi;
        if (k < 6) v = diffs[(b * 10 + t) * 6 + k];
        else if (t > 0) v = roi[((size_t)(b * 10 + t - 1)) * 1024 + k - 6];
      }
      xs[bi][kk] = v;
    }
    __syncthreads();
    int k4 = kc & ~3;
    for (int kk = 0; kk < k4; kk += 4) {
      const float* wp = Wt + (size_t)(k0 + kk) * 1024 + oc;
      float2 w0 = *(const float2*)(wp);
      float2 w1 = *(const float2*)(wp + 1024);
      float2 w2 = *(const float2*)(wp + 2048);
      float2 w3 = *(const float2*)(wp + 3072);
#pragma unroll
      for (int bi = 0; bi < 4; bi++) {
        float4 xv = *(const float4*)&xs[bi][kk];
        acc[0][bi] += w0.x * xv.x + w1.x * xv.y + w2.x * xv.z + w3.x * xv.w;
        acc[1][bi] += w0.y * xv.x + w1.y * xv.y + w2.y * xv.z + w3.y * xv.w;
      }
    }
    for (int kk = k4; kk < kc; kk++) {
      const float* wp = Wt + (size_t)(k0 + kk) * 1024 + oc;
      float2 wv = *(const float2*)wp;
#pragma unroll
      for (int bi = 0; bi < 4; bi++) {
        float xv = xs[bi][kk];
        acc[0][bi] += wv.x * xv;
        acc[1][bi] += wv.y * xv;
      }
    }
  }
  float b0 = bih[oc] + bhh[oc], b1 = bih[oc + 1] + bhh[oc + 1];
  for (int bi = 0; bi < 4; bi++) {
    int b = bq * 4 + bi;
    float* gp = Gx + ((size_t)t * 16 + b) * 1024 + oc;
    gp[0] = acc[0][bi] + b0;
    gp[1] = acc[1][bi] + b1;
  }
}

// ---------------------------------------------------------------------------
// One encoder LSTM step, fused gates + pointwise. grid 8 blocks (2 batches each);
// thread owns 4 consecutive oc of the 1024 gate space, acc over 2 b.
// ---------------------------------------------------------------------------
__global__ __launch_bounds__(256) void enc_step_kernel(const float* __restrict__ hprev,
                                                       const float* __restrict__ cprev,
                                                       const float* __restrict__ Wt,
                                                       const float* __restrict__ Gx_t,
                                                       float* __restrict__ hout,
                                                       float* __restrict__ cout, int first) {
  int bg = blockIdx.x;
  int tid = threadIdx.x;
  int oc0 = tid * 4;
  __shared__ float xs[2][256];
  __shared__ float gl[1024][2];
  float acc[4][2] = {{0.f,0.f},{0.f,0.f},{0.f,0.f},{0.f,0.f}};

  for (int idx = tid; idx < 512; idx += 256) {
    int bi = idx / 256, k = idx % 256;
    xs[bi][k] = first ? 0.f : hprev[(bg * 2 + bi) * 256 + k];
  }
  __syncthreads();

  for (int k = 0; k < 256; k += 4) {
    const float* wp = Wt + (size_t)k * 1024 + oc0;
    float4 w0 = *(const float4*)(wp);
    float4 w1 = *(const float4*)(wp + 1024);
    float4 w2 = *(const float4*)(wp + 2048);
    float4 w3 = *(const float4*)(wp + 3072);
#pragma unroll
    for (int bi = 0; bi < 2; bi++) {
      float4 xv = *(const float4*)&xs[bi][k];
      acc[0][bi] += w0.x * xv.x + w1.x * xv.y + w2.x * xv.z + w3.x * xv.w;
      acc[1][bi] += w0.y * xv.x + w1.y * xv.y + w2.y * xv.z + w3.y * xv.w;
      acc[2][bi] += w0.z * xv.x + w1.z * xv.y + w2.z * xv.z + w3.z * xv.w;
      acc[3][bi] += w0.w * xv.x + w1.w * xv.y + w2.w * xv.z + w3.w * xv.w;
    }
  }
#pragma unroll
  for (int o = 0; o < 4; o++)
#pragma unroll
    for (int bi = 0; bi < 2; bi++)
      gl[oc0 + o][bi] = acc[o][bi] + Gx_t[(bg * 2 + bi) * 1024 + oc0 + o];
  __syncthreads();

  int j = tid;
#pragma unroll
  for (int bi = 0; bi < 2; bi++) {
    float ig = gl[j][bi], fg = gl[256 + j][bi], gg = gl[512 + j][bi], og = gl[768 + j][bi];
    float cold = first ? 0.f : cprev[(bg * 2 + bi) * 256 + j];
    float cn = sigm(fg) * cold + sigm(ig) * tanhf(gg);
    float hn = sigm(og) * tanhf(cn);
    cout[(bg * 2 + bi) * 256 + j] = cn;
    hout[(bg * 2 + bi) * 256 + j] = hn;
  }
}

// ---------------------------------------------------------------------------
// Attention + decoder-input assembly. grid 16 (one block per batch).
// xt[b] = [dec0 (1030), applied (256)]
// ---------------------------------------------------------------------------
__global__ __launch_bounds__(256) void attn_kernel(const float* __restrict__ hall,
                                                   const float* __restrict__ roi,
                                                   const float* __restrict__ attw,
                                                   const float* __restrict__ attb,
                                                   float* __restrict__ xt) {
  int b = blockIdx.x;
  int tid = threadIdx.x;
  __shared__ float part[256][10];
  __shared__ float aw[10];
  float p[10];
#pragma unroll
  for (int l = 0; l < 10; l++) p[l] = 0.f;

  for (int k = tid; k < KDEC; k += 256) {
    float xv;
    if (k < 256) {
      xv = hall[((size_t)9 * 16 + b) * 256 + k];
    } else {
      int kk = k - 256;          // dec0 index
      if (kk < 4) xv = 0.f;
      else if (kk == 4) xv = 1.f;
      else if (kk == 5) xv = 0.f;
      else xv = roi[((size_t)(b * 10 + 9)) * 1024 + kk - 6];
    }
#pragma unroll
    for (int l = 0; l < 10; l++) p[l] += xv * attw[l * KDEC + k];
  }
#pragma unroll
  for (int l = 0; l < 10; l++) part[tid][l] = p[l];
  __syncthreads();
  for (int s = 128; s > 0; s >>= 1) {
    if (tid < s)
#pragma unroll
      for (int l = 0; l < 10; l++) part[tid][l] += part[tid + s][l];
    __syncthreads();
  }
  if (tid == 0) {
    float m = -1e30f;
    float lg[10];
#pragma unroll
    for (int l = 0; l < 10; l++) { lg[l] = part[0][l] + attb[l]; m = fmaxf(m, lg[l]); }
    float s = 0.f;
#pragma unroll
    for (int l = 0; l < 10; l++) { lg[l] = expf(lg[l] - m); s += lg[l]; }
#pragma unroll
    for (int l = 0; l < 10; l++) aw[l] = lg[l] / s;
  }
  __syncthreads();

  // dec0 portion
  for (int k = tid; k < 1030; k += 256) {
    float xv;
    if (k < 4) xv = 0.f;
    else if (k == 4) xv = 1.f;
    else if (k == 5) xv = 0.f;
    else xv = roi[((size_t)(b * 10 + 9)) * 1024 + k - 6];
    xt[(size_t)b * KDEC + k] = xv;
  }
  // applied portion
  {
    int j = tid;
    float s = 0.f;
#pragma unroll
    for (int l = 0; l < 10; l++) s += aw[l] * hall[((size_t)l * 16 + b) * 256 + j];
    xt[(size_t)b * KDEC + 1030 + j] = s;
  }
}

// ---------------------------------------------------------------------------
// Decoder LSTM step (single step, c0 = 0). grid 8 blocks (2 batches each).
// ---------------------------------------------------------------------------
__global__ __launch_bounds__(256) void dec_step_kernel(const float* __restrict__ xt,
                                                       const float* __restrict__ h9,
                                                       const float* __restrict__ Wtx,
                                                       const float* __restrict__ Wth,
                                                       const float* __restrict__ bih,
                                                       const float* __restrict__ bhh,
                                                       float* __restrict__ hout) {
  int bg = blockIdx.x;
  int tid = threadIdx.x;
  int oc0 = tid * 4;
  __shared__ float xs[2][1288];
  __shared__ float hs[2][256];
  __shared__ float gl[1024][2];
  float acc[4][2] = {{0.f,0.f},{0.f,0.f},{0.f,0.f},{0.f,0.f}};

  for (int idx = tid; idx < 2 * KDEC; idx += 256) {
    int bi = idx / KDEC, k = idx % KDEC;
    xs[bi][k] = xt[(size_t)(bg * 2 + bi) * KDEC + k];
  }
  for (int idx = tid; idx < 512; idx += 256) {
    int bi = idx / 256, k = idx % 256;
    hs[bi][k] = h9[(bg * 2 + bi) * 256 + k];
  }
  __syncthreads();

  for (int k = 0; k < 1284; k += 4) {
    const float* wp = Wtx + (size_t)k * 1024 + oc0;
    float4 w0 = *(const float4*)(wp);
    float4 w1 = *(const float4*)(wp + 1024);
    float4 w2 = *(const float4*)(wp + 2048);
    float4 w3 = *(const float4*)(wp + 3072);
#pragma unroll
    for (int bi = 0; bi < 2; bi++) {
      float4 xv = *(const float4*)&xs[bi][k];
      acc[0][bi] += w0.x * xv.x + w1.x * xv.y + w2.x * xv.z + w3.x * xv.w;
      acc[1][bi] += w0.y * xv.x + w1.y * xv.y + w2.y * xv.z + w3.y * xv.w;
      acc[2][bi] += w0.z * xv.x + w1.z * xv.y + w2.z * xv.z + w3.z * xv.w;
      acc[3][bi] += w0.w * xv.x + w1.w * xv.y + w2.w * xv.z + w3.w * xv.w;
    }
  }
  for (int k = 1284; k < KDEC; k++) {
    const float* wp = Wtx + (size_t)k * 1024 + oc0;
    float4 w = *(const float4*)wp;
#pragma unroll
    for (int bi = 0; bi < 2; bi++) {
      float xv = xs[bi][k];
      acc[0][bi] += w.x * xv;
      acc[1][bi] += w.y * xv;
      acc[2][bi] += w.z * xv;
      acc[3][bi] += w.w * xv;
    }
  }
  for (int k = 0; k < 256; k += 4) {
    const float* wp = Wth + (size_t)k * 1024 + oc0;
    float4 w0 = *(const float4*)(wp);
    float4 w1 = *(const float4*)(wp + 1024);
    float4 w2 = *(const float4*)(wp + 2048);
    float4 w3 = *(const float4*)(wp + 3072);
#pragma unroll
    for (int bi = 0; bi < 2; bi++) {
      float4 xv = *(const float4*)&hs[bi][k];
      acc[0][bi] += w0.x * xv.x + w1.x * xv.y + w2.x * xv.z + w3.x * xv.w;
      acc[1][bi] += w0.y * xv.x + w1.y * xv.y + w2.y * xv.z + w3.y * xv.w;
      acc[2][bi] += w0.z * xv.x + w1.z * xv.y + w2.z * xv.z + w3.z * xv.w;
      acc[3][bi] += w0.w * xv.x + w1.w * xv.y + w2.w * xv.z + w3.w * xv.w;
    }
  }
#pragma unroll
  for (int o = 0; o < 4; o++)
#pragma unroll
    for (int bi = 0; bi < 2; bi++)
      gl[oc0 + o][bi] = acc[o][bi] + bih[oc0 + o] + bhh[oc0 + o];
  __syncthreads();

  int j = tid;
#pragma unroll
  for (int bi = 0; bi < 2; bi++) {
    float ig = gl[j][bi], fg = gl[256 + j][bi], gg = gl[512 + j][bi], og = gl[768 + j][bi];
    (void)fg;  // c_prev = 0, forget-gate term vanishes
    float cn = sigm(ig) * tanhf(gg);
    float hn = sigm(og) * tanhf(cn);
    hout[(bg * 2 + bi) * 256 + j] = hn;
  }
}

// ---------------------------------------------------------------------------
// out = relu(h @ lin1.T + b1) @ lin2.T + b2. grid 16 (block per batch).
// ---------------------------------------------------------------------------
__global__ __launch_bounds__(256) void final_kernel(const float* __restrict__ hdec,
                                                    const float* __restrict__ l1w,
                                                    const float* __restrict__ l1b,
                                                    const float* __restrict__ l2w,
                                                    const float* __restrict__ l2b,
                                                    float* __restrict__ out) {
  int b = blockIdx.x;
  int tid = threadIdx.x;
  __shared__ float hsm[256];
  __shared__ float y1[256];
  hsm[tid] = hdec[b * 256 + tid];
  __syncthreads();
  float a = l1b[tid];
  for (int k = 0; k < 256; k++) a = fmaf(hsm[k], l1w[(size_t)tid * 256 + k], a);
  y1[tid] = fmaxf(a, 0.f);
  __syncthreads();
  if (tid < 6) {
    float s = l2b[tid];
    for (int k = 0; k < 256; k++) s = fmaf(y1[k], l2w[(size_t)tid * 256 + k], s);
    out[b * 6 + tid] = s;
  }
}

}  // namespace

extern "C" void kernel_launch(void* const* d_in, const int* in_sizes, int n_in,
                              void* d_out, int out_size, void* d_ws, size_t ws_size,
                              hipStream_t stream) {
  const float* diffs = (const float*)d_in[0];
  const float* boxes = (const float*)d_in[2];
  const float* feat  = (const float*)d_in[3];
  const int*   isz   = (const int*)d_in[4];
  const float* c31w  = (const float*)d_in[6];
  const float* c31b  = (const float*)d_in[7];
  const float* c4w   = (const float*)d_in[8];
  const float* c4b   = (const float*)d_in[9];
  const float* c41w  = (const float*)d_in[10];
  const float* c41b  = (const float*)d_in[11];
  const float* eWih  = (const float*)d_in[12];
  const float* eWhh  = (const float*)d_in[13];
  const float* ebih  = (const float*)d_in[14];
  const float* ebhh  = (const float*)d_in[15];
  const float* attw  = (const float*)d_in[16];
  const float* attb  = (const float*)d_in[17];
  const float* dWih  = (const float*)d_in[18];
  const float* dWhh  = (const float*)d_in[19];
  const float* dbih  = (const float*)d_in[20];
  const float* dbhh  = (const float*)d_in[21];
  const float* l1w   = (const float*)d_in[22];
  const float* l1b   = (const float*)d_in[23];
  const float* l2w   = (const float*)d_in[24];
  const float* l2b   = (const float*)d_in[25];

  // ---- workspace layout: persistent region first, then chunked conv region --
  float* ws = (float*)d_ws;
  size_t off = 0;
  float* roiB  = ws + off; off += (size_t)NPAIR * 1024;          //   163,840
  float* WtIh  = ws + off; off += (size_t)INSZ * 1024;           // 1,054,720
  float* WtHh  = ws + off; off += (size_t)256 * 1024;            //   262,144
  float* WtDih = ws + off; off += (size_t)KDEC * 1024;           // 1,316,864
  float* WtDhh = ws + off; off += (size_t)256 * 1024;            //   262,144
  float* Gx    = ws + off; off += (size_t)10 * 16 * 1024;        //   163,840
  float* hall  = ws + off; off += (size_t)10 * 16 * 256;         //    40,960
  float* cb0   = ws + off; off += (size_t)16 * 256;
  float* cb1   = ws + off; off += (size_t)16 * 256;
  float* xt    = ws + off; off += (size_t)16 * KDEC;
  float* hdec  = ws + off; off += (size_t)16 * 256;
  const size_t persistent = off;                                 // ~3.30 M floats

  // per-pair chunk scratch: corr(81*HW) + c3(128*HW) + c4(128*HW); c41 aliases corr
  const size_t perPair = (size_t)(81 + 128 + 128) * HW;          // 339,696 floats
  size_t wsFloats = ws_size / sizeof(float);
  size_t avail = (wsFloats > persistent) ? (wsFloats - persistent) : 0;
  int K = (int)(avail / perPair);
  if (K < 1) K = 1;            // below this we cannot shrink further
  if (K > NPAIR) K = NPAIR;

  float* corr = ws + persistent;                  // [K][81][HW]
  float* c3   = corr + (size_t)K * 81 * HW;       // [K][128][HW]
  float* c4   = c3 + (size_t)K * 128 * HW;        // [K][128][HW]
  float* c41  = corr;                             // corr dead after conv3_1; 64*HW < 81*HW

  transpose_kernel<<<dim3((1030 + 31) / 32, 32), 256, 0, stream>>>(eWih, WtIh, 1024, 1030);
  transpose_kernel<<<dim3(8, 32), 256, 0, stream>>>(eWhh, WtHh, 1024, 256);
  transpose_kernel<<<dim3((1286 + 31) / 32, 32), 256, 0, stream>>>(dWih, WtDih, 1024, 1286);
  transpose_kernel<<<dim3(8, 32), 256, 0, stream>>>(dWhh, WtDhh, 1024, 256);

  for (int k0 = 0; k0 < NPAIR; k0 += K) {
    int Kc = (k0 + K <= NPAIR) ? K : (NPAIR - k0);
    corr_kernel<<<dim3(Kc, 6), 256, 0, stream>>>(feat, corr, k0);
    conv_kernel<81, 128><<<dim3(Kc, 8), 256, 0, stream>>>(corr, c31w, c31b, c3);
    conv_kernel<128, 128><<<dim3(Kc, 8), 256, 0, stream>>>(c3, c4w, c4b, c4);
    conv_kernel<128, 64><<<dim3(Kc, 4), 256, 0, stream>>>(c4, c41w, c41b, c41);
    roi_kernel<<<Kc, 256, 0, stream>>>(c41, boxes, isz, roiB, k0);
  }

  gx_kernel<<<dim3(10, 4, 2), 256, 0, stream>>>(diffs, roiB, WtIh, ebih, ebhh, Gx);
  float* cbuf[2] = {cb0, cb1};
  for (int t = 0; t < 10; t++) {
    const float* hp = (t == 0) ? hall : hall + (size_t)(t - 1) * 16 * 256;
    const float* cp = cbuf[(t + 1) & 1];
    enc_step_kernel<<<8, 256, 0, stream>>>(hp, cp, WtHh, Gx + (size_t)t * 16 * 1024,
                                           hall + (size_t)t * 16 * 256, cbuf[t & 1],
                                           t == 0 ? 1 : 0);
  }
  attn_kernel<<<16, 256, 0, stream>>>(hall, roiB, attw, attb, xt);
  dec_step_kernel<<<8, 256, 0, stream>>>(xt, hall + (size_t)9 * 16 * 256, WtDih, WtDhh,
                                         dbih, dbhh, hdec);
  final_kernel<<<16, 256, 0, stream>>>(hdec, l1w, l1b, l2w, l2b, (float*)d_out);
}

// Round 5
// 2327.475 us; speedup vs baseline: 2.0144x; 2.0144x over previous
//
#include <hip/hip_runtime.h>
#include <math.h>

#define DEVI __device__ __forceinline__

namespace {

typedef unsigned short ushort_t;
typedef __attribute__((ext_vector_type(8))) short bf16x8;
typedef __attribute__((ext_vector_type(4))) short short4v;
typedef __attribute__((ext_vector_type(4))) unsigned short ushort4v;
typedef __attribute__((ext_vector_type(4))) float f32x4;

constexpr int NPAIR = 160;          // kept frame pairs
constexpr int NFRM  = 176;          // total frames (16 tracks x 11)
constexpr int HFc   = 24, WFc = 42, HW = HFc * WFc;   // 1008 px
constexpr int INSZ  = 1030;
constexpr int KDEC  = 1286;

DEVI float sigm(float x) { return 1.f / (1.f + expf(-x)); }
DEVI float lrelu(float v) { return v > 0.f ? v : 0.1f * v; }

DEVI ushort_t f2bf(float f) {           // fp32 -> bf16 RNE
  unsigned int u = __float_as_uint(f);
  u = (u + 0x7FFF + ((u >> 16) & 1)) >> 16;
  return (ushort_t)u;
}
DEVI float ldbf(const ushort_t* p) {    // bf16 -> fp32
  return __uint_as_float(((unsigned int)*p) << 16);
}
DEVI bf16x8 pack8(short4v lo, short4v hi) {
  bf16x8 r;
  r[0] = lo[0]; r[1] = lo[1]; r[2] = lo[2]; r[3] = lo[3];
  r[4] = hi[0]; r[5] = hi[1]; r[6] = hi[2]; r[7] = hi[3];
  return r;
}

// ---------------------------------------------------------------------------
// feat fp32 [frame][256][1008] -> featT bf16 [frame][1008][256] (channels-last)
// ---------------------------------------------------------------------------
__global__ __launch_bounds__(256) void feat_to_bf16cl(const float* __restrict__ src,
                                                      ushort_t* __restrict__ dst) {
  int fr = blockIdx.z;
  int p0 = blockIdx.x * 32, c0 = blockIdx.y * 32;
  __shared__ float t[32][33];
  int tx = threadIdx.x % 32, ty = threadIdx.x / 32;
  const float* s = src + (size_t)fr * 256 * HW;
#pragma unroll
  for (int i = 0; i < 32; i += 8) {
    int c = c0 + ty + i, pp = p0 + tx;
    t[ty + i][tx] = (pp < HW) ? s[(size_t)c * HW + pp] : 0.f;
  }
  __syncthreads();
  ushort_t* d = dst + (size_t)fr * HW * 256;
#pragma unroll
  for (int i = 0; i < 32; i += 8) {
    int pp = p0 + ty + i, c = c0 + tx;
    if (pp < HW) d[(size_t)pp * 256 + c] = f2bf(t[tx][ty + i]);
  }
}

// ---------------------------------------------------------------------------
// weight reorder: W fp32 [OC][IC][3][3] -> bf16 [oc][kpos][ICP], zero-padded
// ---------------------------------------------------------------------------
template <int IC, int ICP>
__global__ __launch_bounds__(256) void wreorder_kernel(const float* __restrict__ w,
                                                       ushort_t* __restrict__ o) {
  int oc = blockIdx.x;
  for (int idx = threadIdx.x; idx < 9 * ICP; idx += 256) {
    int kp = idx / ICP, ic = idx % ICP;
    float v = (ic < IC) ? w[((size_t)oc * IC + ic) * 9 + kp] : 0.f;
    o[(size_t)oc * 9 * ICP + idx] = f2bf(v);
  }
}

__global__ void zero_kernel(uint4* __restrict__ p, size_t n16) {
  uint4 z = {0u, 0u, 0u, 0u};
  for (size_t i = blockIdx.x * 256ull + threadIdx.x; i < n16; i += (size_t)gridDim.x * 256)
    p[i] = z;
}

// ---------------------------------------------------------------------------
// Correlation via banded Gram MFMA. Block (pair, y), 3 waves (one per 16-x tile).
// No LDS: A/B fragments are direct per-lane 8B global loads from featT.
// corr_cl bf16 [pair][1008][96] (ch = dy*9+dx, pads/invalid stay pre-zeroed).
// ---------------------------------------------------------------------------
__global__ __launch_bounds__(192) void corr_mfma_kernel(const ushort_t* __restrict__ featT,
                                                        ushort_t* __restrict__ corr_cl) {
  int kk = blockIdx.x, y = blockIdx.y;
  int g = kk + kk / 10;
  int wid = threadIdx.x >> 6, lane = threadIdx.x & 63;
  int x0 = wid * 16;
  int ln = lane & 15, lh = lane >> 4;
  const ushort_t* f1 = featT + ((size_t)g * HW + y * WFc) * 256;
  const ushort_t* f2b = featT + (size_t)(g + 1) * HW * 256;

  bf16x8 af[8];
  {
    const ushort_t* ap = f1 + (size_t)(x0 + ln) * 256 + lh * 4;
#pragma unroll
    for (int kc = 0; kc < 8; kc++) {
      short4v lo = *(const short4v*)(ap + kc * 32);
      short4v hi = *(const short4v*)(ap + kc * 32 + 16);
      af[kc] = pack8(lo, hi);
    }
  }

  for (int dy = 0; dy < 9; dy++) {
    int y2 = y + dy - 4;
    if (y2 < 0 || y2 >= HFc) continue;          // zero-padded rows: outputs stay 0
    const ushort_t* f2r = f2b + (size_t)y2 * WFc * 256;
#pragma unroll
    for (int jt = 0; jt < 2; jt++) {
      int j0 = x0 - 4 + jt * 16;
      int j = j0 + ln;
      f32x4 acc = {0.f, 0.f, 0.f, 0.f};
      const ushort_t* bp = f2r + (long)j * 256 + lh * 4;   // j may be <0: prev-frame tail, masked at store
#pragma unroll
      for (int kc = 0; kc < 8; kc++) {
        short4v lo = *(const short4v*)(bp + kc * 32);
        short4v hi = *(const short4v*)(bp + kc * 32 + 16);
        acc = __builtin_amdgcn_mfma_f32_16x16x32_bf16(af[kc], pack8(lo, hi), acc, 0, 0, 0);
      }
#pragma unroll
      for (int q = 0; q < 4; q++) {
        int x = x0 + lh * 4 + q;
        int dx = j - x + 4;
        if (x < WFc && j >= 0 && j < WFc && dx >= 0 && dx < 9) {
          float v = lrelu(acc[q] * (1.f / 256.f));
          corr_cl[((size_t)kk * HW + y * WFc + x) * 96 + dy * 9 + dx] = f2bf(v);
        }
      }
    }
  }
}

// ---------------------------------------------------------------------------
// 3x3 conv pad-1 + lrelu as implicit GEMM MFMA. in/out channels-last bf16.
// Block: (image n, group of 3 pixel-tiles). 4 waves; each wave MT oc-tiles x 3 n-tiles.
// ---------------------------------------------------------------------------
template <int ICP, int OC>
__global__ __launch_bounds__(256) void conv_mfma_kernel(const ushort_t* __restrict__ in,
                                                        const ushort_t* __restrict__ wgt,
                                                        const float* __restrict__ bias,
                                                        ushort_t* __restrict__ out) {
  constexpr int MT = (OC == 128) ? 2 : 1;
  int n = blockIdx.x, ntg = blockIdx.y;
  int wid = threadIdx.x >> 6, lane = threadIdx.x & 63;
  int ln = lane & 15, lh = lane >> 4;
  int mt0 = wid * MT;

  f32x4 acc[MT][3];
#pragma unroll
  for (int m = 0; m < MT; m++)
#pragma unroll
    for (int j = 0; j < 3; j++) acc[m][j] = (f32x4){0.f, 0.f, 0.f, 0.f};

  int p[3], px[3], py[3];
#pragma unroll
  for (int j = 0; j < 3; j++) {
    p[j] = (ntg * 3 + j) * 16 + ln;
    px[j] = p[j] % WFc;
    py[j] = p[j] / WFc;
  }
  const ushort_t* inb = in + (size_t)n * HW * ICP;

  for (int kp = 0; kp < 9; kp++) {
    int dyk = kp / 3 - 1, dxk = kp % 3 - 1;
    int delta = dyk * WFc + dxk;
    bool v[3];
#pragma unroll
    for (int j = 0; j < 3; j++)
      v[j] = ((unsigned)(px[j] + dxk) < (unsigned)WFc) && ((unsigned)(py[j] + dyk) < (unsigned)HFc);
#pragma unroll
    for (int c0 = 0; c0 < ICP; c0 += 32) {
      bf16x8 bf[3];
#pragma unroll
      for (int j = 0; j < 3; j++) {
        if (v[j]) {
          const ushort_t* bp = inb + (size_t)(p[j] + delta) * ICP + c0 + lh * 4;
          short4v lo = *(const short4v*)(bp);
          short4v hi = *(const short4v*)(bp + 16);
          bf[j] = pack8(lo, hi);
        } else {
          short4v z = {0, 0, 0, 0};
          bf[j] = pack8(z, z);
        }
      }
#pragma unroll
      for (int m = 0; m < MT; m++) {
        const ushort_t* ap = wgt + ((size_t)((mt0 + m) * 16 + ln) * 9 + kp) * ICP + c0 + lh * 4;
        short4v lo = *(const short4v*)(ap);
        short4v hi = *(const short4v*)(ap + 16);
        bf16x8 af = pack8(lo, hi);
#pragma unroll
        for (int j = 0; j < 3; j++)
          acc[m][j] = __builtin_amdgcn_mfma_f32_16x16x32_bf16(af, bf[j], acc[m][j], 0, 0, 0);
      }
    }
  }

#pragma unroll
  for (int m = 0; m < MT; m++) {
    int ocb = (mt0 + m) * 16 + lh * 4;
#pragma unroll
    for (int j = 0; j < 3; j++) {
      ushort4v pk;
#pragma unroll
      for (int q = 0; q < 4; q++) {
        float vv = lrelu(acc[m][j][q] + bias[ocb + q]);
        pk[q] = f2bf(vv);
      }
      *(ushort4v*)(out + ((size_t)n * HW + p[j]) * OC + ocb) = pk;
    }
  }
}

// ---------------------------------------------------------------------------
// ROI align (torchvision aligned=False), channels-last bf16 input [pair][1008][64].
// Output format identical to round-4: out[k][c*16 + py*4 + px] fp32.
// ---------------------------------------------------------------------------
DEVI float bilinear_cl(const ushort_t* __restrict__ f, float y, float x) {
  bool valid = (y >= -1.f) && (y <= (float)HFc) && (x >= -1.f) && (x <= (float)WFc);
  if (!valid) return 0.f;
  y = fmaxf(y, 0.f);
  x = fmaxf(x, 0.f);
  int y0 = min((int)floorf(y), HFc - 1);
  int x0 = min((int)floorf(x), WFc - 1);
  int y1 = min(y0 + 1, HFc - 1);
  int x1 = min(x0 + 1, WFc - 1);
  if (y0 >= HFc - 1) y = (float)y0;
  if (x0 >= WFc - 1) x = (float)x0;
  float ly = y - y0, lx = x - x0, hy = 1.f - ly, hx = 1.f - lx;
  return hy * hx * ldbf(f + (size_t)(y0 * WFc + x0) * 64) +
         hy * lx * ldbf(f + (size_t)(y0 * WFc + x1) * 64) +
         ly * hx * ldbf(f + (size_t)(y1 * WFc + x0) * 64) +
         ly * lx * ldbf(f + (size_t)(y1 * WFc + x1) * 64);
}

__global__ __launch_bounds__(256) void roi_cl_kernel(const ushort_t* __restrict__ feat,
                                                     const float* __restrict__ boxes,
                                                     const int* __restrict__ isz,
                                                     float* __restrict__ out) {
  int k = blockIdx.x;
  int g = k + k / 10;
  float scale = 24.0f / (float)isz[0];
  float x1 = boxes[g * 4 + 0] * scale, y1 = boxes[g * 4 + 1] * scale;
  float x2 = boxes[g * 4 + 2] * scale, y2 = boxes[g * 4 + 3] * scale;
  float bw = fmaxf(x2 - x1, 1.0f) * 0.25f;
  float bh = fmaxf(y2 - y1, 1.0f) * 0.25f;
  int tid = threadIdx.x;
  int c = tid & 63, bq = tid >> 6;
  const ushort_t* f = feat + (size_t)k * HW * 64 + c;
#pragma unroll
  for (int i = 0; i < 4; i++) {
    int bin = bq * 4 + i;
    int pyb = bin / 4, pxb = bin % 4;
    float s = 0.f;
#pragma unroll
    for (int sy = 0; sy < 2; sy++)
#pragma unroll
      for (int sx = 0; sx < 2; sx++) {
        float yy = y1 + (pyb + (sy + 0.5f) * 0.5f) * bh;
        float xx = x1 + (pxb + (sx + 0.5f) * 0.5f) * bw;
        s += bilinear_cl(f, yy, xx);
      }
    out[(size_t)k * 1024 + c * 16 + pyb * 4 + pxb] = s * 0.25f;
  }
}

// ---------------------------------------------------------------------------
// 32x32 LDS-tiled transpose: src[R][C] -> dst[C][R]  (LSTM weights, fp32)
// ---------------------------------------------------------------------------
__global__ __launch_bounds__(256) void transpose_kernel(const float* __restrict__ src,
                                                        float* __restrict__ dst, int R, int C) {
  __shared__ float t[32][33];
  int bx = blockIdx.x * 32, by = blockIdx.y * 32;
  int tx = threadIdx.x % 32, ty = threadIdx.x / 32;
  for (int i = 0; i < 32; i += 8) {
    int r = by + ty + i, c = bx + tx;
    t[ty + i][tx] = (r < R && c < C) ? src[(size_t)r * C + c] : 0.f;
  }
  __syncthreads();
  for (int i = 0; i < 32; i += 8) {
    int c = bx + ty + i, r = by + tx;
    if (c < C && r < R) dst[(size_t)c * R + r] = t[tx][ty + i];
  }
}

// ---------------------------------------------------------------------------
// G_x[t][b][oc] = sum_k enc_in[b][t][k] * Wt[k][oc] + bih[oc] + bhh[oc]
// ---------------------------------------------------------------------------
__global__ __launch_bounds__(256) void gx_kernel(const float* __restrict__ diffs,
                                                 const float* __restrict__ roi,
                                                 const float* __restrict__ Wt,
                                                 const float* __restrict__ bih,
                                                 const float* __restrict__ bhh,
                                                 float* __restrict__ Gx) {
  int t = blockIdx.x, bq = blockIdx.y, och = blockIdx.z;
  int tid = threadIdx.x;
  int oc = och * 512 + tid * 2;
  __shared__ float xs[4][256];
  float acc[2][4] = {{0.f, 0.f, 0.f, 0.f}, {0.f, 0.f, 0.f, 0.f}};

  for (int k0 = 0; k0 < INSZ; k0 += 256) {
    int kc = min(256, INSZ - k0);
    __syncthreads();
    for (int idx = tid; idx < 4 * 256; idx += 256) {
      int bi = idx / 256, kk = idx % 256;
      float v = 0.f;
      int k = k0 + kk;
      if (kk < kc) {
        int b = bq * 4 + bi;
        if (k < 6) v = diffs[(b * 10 + t) * 6 + k];
        else if (t > 0) v = roi[((size_t)(b * 10 + t - 1)) * 1024 + k - 6];
      }
      xs[bi][kk] = v;
    }
    __syncthreads();
    int k4 = kc & ~3;
    for (int kk = 0; kk < k4; kk += 4) {
      const float* wp = Wt + (size_t)(k0 + kk) * 1024 + oc;
      float2 w0 = *(const float2*)(wp);
      float2 w1 = *(const float2*)(wp + 1024);
      float2 w2 = *(const float2*)(wp + 2048);
      float2 w3 = *(const float2*)(wp + 3072);
#pragma unroll
      for (int bi = 0; bi < 4; bi++) {
        float4 xv = *(const float4*)&xs[bi][kk];
        acc[0][bi] += w0.x * xv.x + w1.x * xv.y + w2.x * xv.z + w3.x * xv.w;
        acc[1][bi] += w0.y * xv.x + w1.y * xv.y + w2.y * xv.z + w3.y * xv.w;
      }
    }
    for (int kk = k4; kk < kc; kk++) {
      const float* wp = Wt + (size_t)(k0 + kk) * 1024 + oc;
      float2 wv = *(const float2*)wp;
#pragma unroll
      for (int bi = 0; bi < 4; bi++) {
        float xv = xs[bi][kk];
        acc[0][bi] += wv.x * xv;
        acc[1][bi] += wv.y * xv;
      }
    }
  }
  float b0 = bih[oc] + bhh[oc], b1 = bih[oc + 1] + bhh[oc + 1];
  for (int bi = 0; bi < 4; bi++) {
    int b = bq * 4 + bi;
    float* gp = Gx + ((size_t)t * 16 + b) * 1024 + oc;
    gp[0] = acc[0][bi] + b0;
    gp[1] = acc[1][bi] + b1;
  }
}

// ---------------------------------------------------------------------------
// One encoder LSTM step, fused gates + pointwise.
// ---------------------------------------------------------------------------
__global__ __launch_bounds__(256) void enc_step_kernel(const float* __restrict__ hprev,
                                                       const float* __restrict__ cprev,
                                                       const float* __restrict__ Wt,
                                                       const float* __restrict__ Gx_t,
                                                       float* __restrict__ hout,
                                                       float* __restrict__ cout, int first) {
  int bg = blockIdx.x;
  int tid = threadIdx.x;
  int oc0 = tid * 4;
  __shared__ float xs[2][256];
  __shared__ float gl[1024][2];
  float acc[4][2] = {{0.f,0.f},{0.f,0.f},{0.f,0.f},{0.f,0.f}};

  for (int idx = tid; idx < 512; idx += 256) {
    int bi = idx / 256, k = idx % 256;
    xs[bi][k] = first ? 0.f : hprev[(bg * 2 + bi) * 256 + k];
  }
  __syncthreads();

  for (int k = 0; k < 256; k += 4) {
    const float* wp = Wt + (size_t)k * 1024 + oc0;
    float4 w0 = *(const float4*)(wp);
    float4 w1 = *(const float4*)(wp + 1024);
    float4 w2 = *(const float4*)(wp + 2048);
    float4 w3 = *(const float4*)(wp + 3072);
#pragma unroll
    for (int bi = 0; bi < 2; bi++) {
      float4 xv = *(const float4*)&xs[bi][k];
      acc[0][bi] += w0.x * xv.x + w1.x * xv.y + w2.x * xv.z + w3.x * xv.w;
      acc[1][bi] += w0.y * xv.x + w1.y * xv.y + w2.y * xv.z + w3.y * xv.w;
      acc[2][bi] += w0.z * xv.x + w1.z * xv.y + w2.z * xv.z + w3.z * xv.w;
      acc[3][bi] += w0.w * xv.x + w1.w * xv.y + w2.w * xv.z + w3.w * xv.w;
    }
  }
#pragma unroll
  for (int o = 0; o < 4; o++)
#pragma unroll
    for (int bi = 0; bi < 2; bi++)
      gl[oc0 + o][bi] = acc[o][bi] + Gx_t[(bg * 2 + bi) * 1024 + oc0 + o];
  __syncthreads();

  int j = tid;
#pragma unroll
  for (int bi = 0; bi < 2; bi++) {
    float ig = gl[j][bi], fg = gl[256 + j][bi], gg = gl[512 + j][bi], og = gl[768 + j][bi];
    float cold = first ? 0.f : cprev[(bg * 2 + bi) * 256 + j];
    float cn = sigm(fg) * cold + sigm(ig) * tanhf(gg);
    float hn = sigm(og) * tanhf(cn);
    cout[(bg * 2 + bi) * 256 + j] = cn;
    hout[(bg * 2 + bi) * 256 + j] = hn;
  }
}

// ---------------------------------------------------------------------------
// Attention + decoder-input assembly.
// ---------------------------------------------------------------------------
__global__ __launch_bounds__(256) void attn_kernel(const float* __restrict__ hall,
                                                   const float* __restrict__ roi,
                                                   const float* __restrict__ attw,
                                                   const float* __restrict__ attb,
                                                   float* __restrict__ xt) {
  int b = blockIdx.x;
  int tid = threadIdx.x;
  __shared__ float part[256][10];
  __shared__ float aw[10];
  float p[10];
#pragma unroll
  for (int l = 0; l < 10; l++) p[l] = 0.f;

  for (int k = tid; k < KDEC; k += 256) {
    float xv;
    if (k < 256) {
      xv = hall[((size_t)9 * 16 + b) * 256 + k];
    } else {
      int kk = k - 256;
      if (kk < 4) xv = 0.f;
      else if (kk == 4) xv = 1.f;
      else if (kk == 5) xv = 0.f;
      else xv = roi[((size_t)(b * 10 + 9)) * 1024 + kk - 6];
    }
#pragma unroll
    for (int l = 0; l < 10; l++) p[l] += xv * attw[l * KDEC + k];
  }
#pragma unroll
  for (int l = 0; l < 10; l++) part[tid][l] = p[l];
  __syncthreads();
  for (int s = 128; s > 0; s >>= 1) {
    if (tid < s)
#pragma unroll
      for (int l = 0; l < 10; l++) part[tid][l] += part[tid + s][l];
    __syncthreads();
  }
  if (tid == 0) {
    float m = -1e30f;
    float lg[10];
#pragma unroll
    for (int l = 0; l < 10; l++) { lg[l] = part[0][l] + attb[l]; m = fmaxf(m, lg[l]); }
    float s = 0.f;
#pragma unroll
    for (int l = 0; l < 10; l++) { lg[l] = expf(lg[l] - m); s += lg[l]; }
#pragma unroll
    for (int l = 0; l < 10; l++) aw[l] = lg[l] / s;
  }
  __syncthreads();

  for (int k = tid; k < 1030; k += 256) {
    float xv;
    if (k < 4) xv = 0.f;
    else if (k == 4) xv = 1.f;
    else if (k == 5) xv = 0.f;
    else xv = roi[((size_t)(b * 10 + 9)) * 1024 + k - 6];
    xt[(size_t)b * KDEC + k] = xv;
  }
  {
    int j = tid;
    float s = 0.f;
#pragma unroll
    for (int l = 0; l < 10; l++) s += aw[l] * hall[((size_t)l * 16 + b) * 256 + j];
    xt[(size_t)b * KDEC + 1030 + j] = s;
  }
}

// ---------------------------------------------------------------------------
// Decoder LSTM step (single step, c0 = 0).
// ---------------------------------------------------------------------------
__global__ __launch_bounds__(256) void dec_step_kernel(const float* __restrict__ xt,
                                                       const float* __restrict__ h9,
                                                       const float* __restrict__ Wtx,
                                                       const float* __restrict__ Wth,
                                                       const float* __restrict__ bih,
                                                       const float* __restrict__ bhh,
                                                       float* __restrict__ hout) {
  int bg = blockIdx.x;
  int tid = threadIdx.x;
  int oc0 = tid * 4;
  __shared__ float xs[2][1288];
  __shared__ float hs[2][256];
  __shared__ float gl[1024][2];
  float acc[4][2] = {{0.f,0.f},{0.f,0.f},{0.f,0.f},{0.f,0.f}};

  for (int idx = tid; idx < 2 * KDEC; idx += 256) {
    int bi = idx / KDEC, k = idx % KDEC;
    xs[bi][k] = xt[(size_t)(bg * 2 + bi) * KDEC + k];
  }
  for (int idx = tid; idx < 512; idx += 256) {
    int bi = idx / 256, k = idx % 256;
    hs[bi][k] = h9[(bg * 2 + bi) * 256 + k];
  }
  __syncthreads();

  for (int k = 0; k < 1284; k += 4) {
    const float* wp = Wtx + (size_t)k * 1024 + oc0;
    float4 w0 = *(const float4*)(wp);
    float4 w1 = *(const float4*)(wp + 1024);
    float4 w2 = *(const float4*)(wp + 2048);
    float4 w3 = *(const float4*)(wp + 3072);
#pragma unroll
    for (int bi = 0; bi < 2; bi++) {
      float4 xv = *(const float4*)&xs[bi][k];
      acc[0][bi] += w0.x * xv.x + w1.x * xv.y + w2.x * xv.z + w3.x * xv.w;
      acc[1][bi] += w0.y * xv.x + w1.y * xv.y + w2.y * xv.z + w3.y * xv.w;
      acc[2][bi] += w0.z * xv.x + w1.z * xv.y + w2.z * xv.z + w3.z * xv.w;
      acc[3][bi] += w0.w * xv.x + w1.w * xv.y + w2.w * xv.z + w3.w * xv.w;
    }
  }
  for (int k = 1284; k < KDEC; k++) {
    const float* wp = Wtx + (size_t)k * 1024 + oc0;
    float4 w = *(const float4*)wp;
#pragma unroll
    for (int bi = 0; bi < 2; bi++) {
      float xv = xs[bi][k];
      acc[0][bi] += w.x * xv;
      acc[1][bi] += w.y * xv;
      acc[2][bi] += w.z * xv;
      acc[3][bi] += w.w * xv;
    }
  }
  for (int k = 0; k < 256; k += 4) {
    const float* wp = Wth + (size_t)k * 1024 + oc0;
    float4 w0 = *(const float4*)(wp);
    float4 w1 = *(const float4*)(wp + 1024);
    float4 w2 = *(const float4*)(wp + 2048);
    float4 w3 = *(const float4*)(wp + 3072);
#pragma unroll
    for (int bi = 0; bi < 2; bi++) {
      float4 xv = *(const float4*)&hs[bi][k];
      acc[0][bi] += w0.x * xv.x + w1.x * xv.y + w2.x * xv.z + w3.x * xv.w;
      acc[1][bi] += w0.y * xv.x + w1.y * xv.y + w2.y * xv.z + w3.y * xv.w;
      acc[2][bi] += w0.z * xv.x + w1.z * xv.y + w2.z * xv.z + w3.z * xv.w;
      acc[3][bi] += w0.w * xv.x + w1.w * xv.y + w2.w * xv.z + w3.w * xv.w;
    }
  }
#pragma unroll
  for (int o = 0; o < 4; o++)
#pragma unroll
    for (int bi = 0; bi < 2; bi++)
      gl[oc0 + o][bi] = acc[o][bi] + bih[oc0 + o] + bhh[oc0 + o];
  __syncthreads();

  int j = tid;
#pragma unroll
  for (int bi = 0; bi < 2; bi++) {
    float ig = gl[j][bi], fg = gl[256 + j][bi], gg = gl[512 + j][bi], og = gl[768 + j][bi];
    (void)fg;
    float cn = sigm(ig) * tanhf(gg);
    float hn = sigm(og) * tanhf(cn);
    hout[(bg * 2 + bi) * 256 + j] = hn;
  }
}

// ---------------------------------------------------------------------------
// out = relu(h @ lin1.T + b1) @ lin2.T + b2.
// ---------------------------------------------------------------------------
__global__ __launch_bounds__(256) void final_kernel(const float* __restrict__ hdec,
                                                    const float* __restrict__ l1w,
                                                    const float* __restrict__ l1b,
                                                    const float* __restrict__ l2w,
                                                    const float* __restrict__ l2b,
                                                    float* __restrict__ out) {
  int b = blockIdx.x;
  int tid = threadIdx.x;
  __shared__ float hsm[256];
  __shared__ float y1[256];
  hsm[tid] = hdec[b * 256 + tid];
  __syncthreads();
  float a = l1b[tid];
  for (int k = 0; k < 256; k++) a = fmaf(hsm[k], l1w[(size_t)tid * 256 + k], a);
  y1[tid] = fmaxf(a, 0.f);
  __syncthreads();
  if (tid < 6) {
    float s = l2b[tid];
    for (int k = 0; k < 256; k++) s = fmaf(y1[k], l2w[(size_t)tid * 256 + k], s);
    out[b * 6 + tid] = s;
  }
}

}  // namespace

extern "C" void kernel_launch(void* const* d_in, const int* in_sizes, int n_in,
                              void* d_out, int out_size, void* d_ws, size_t ws_size,
                              hipStream_t stream) {
  const float* diffs = (const float*)d_in[0];
  const float* boxes = (const float*)d_in[2];
  const float* feat  = (const float*)d_in[3];
  const int*   isz   = (const int*)d_in[4];
  const float* c31w  = (const float*)d_in[6];
  const float* c31b  = (const float*)d_in[7];
  const float* c4w   = (const float*)d_in[8];
  const float* c4b   = (const float*)d_in[9];
  const float* c41w  = (const float*)d_in[10];
  const float* c41b  = (const float*)d_in[11];
  const float* eWih  = (const float*)d_in[12];
  const float* eWhh  = (const float*)d_in[13];
  const float* ebih  = (const float*)d_in[14];
  const float* ebhh  = (const float*)d_in[15];
  const float* attw  = (const float*)d_in[16];
  const float* attb  = (const float*)d_in[17];
  const float* dWih  = (const float*)d_in[18];
  const float* dWhh  = (const float*)d_in[19];
  const float* dbih  = (const float*)d_in[20];
  const float* dbhh  = (const float*)d_in[21];
  const float* l1w   = (const float*)d_in[22];
  const float* l1b   = (const float*)d_in[23];
  const float* l2w   = (const float*)d_in[24];
  const float* l2b   = (const float*)d_in[25];

  // ---- workspace (byte-based, 256B-aligned regions, aliasing planned) ----
  char* base = (char*)d_ws;
  size_t off = 0;
  auto alloc = [&](size_t bytes) {
    char* p = base + off;
    off = (off + bytes + 255) & ~(size_t)255;
    return p;
  };
  const size_t featT_bytes = ((size_t)NFRM * HW + 64) * 256 * 2;   // 90.9 MB (+pad row)
  const size_t c3_bytes    = (size_t)NPAIR * HW * 128 * 2;         // 41.3 MB
  const size_t corr_bytes  = (size_t)NPAIR * HW * 96 * 2;          // 31.0 MB
  const size_t c41_bytes   = (size_t)NPAIR * HW * 64 * 2;          // 20.6 MB
  const size_t c4_bytes    = (size_t)NPAIR * HW * 128 * 2;

  char* regA = alloc(featT_bytes > c3_bytes ? featT_bytes : c3_bytes);  // featT, later c3
  char* regB = alloc(corr_bytes > c41_bytes ? corr_bytes : c41_bytes);  // corr_cl, later c41
  char* regC = alloc(c4_bytes);                                         // c4
  ushort_t* featT   = (ushort_t*)regA;
  ushort_t* c3_cl   = (ushort_t*)regA;   // aliases featT (dead after corr)
  ushort_t* corr_cl = (ushort_t*)regB;
  ushort_t* c41_cl  = (ushort_t*)regB;   // aliases corr_cl (dead after conv3_1)
  ushort_t* c4_cl   = (ushort_t*)regC;

  ushort_t* W31cl = (ushort_t*)alloc((size_t)128 * 9 * 96 * 2);
  ushort_t* W4cl  = (ushort_t*)alloc((size_t)128 * 9 * 128 * 2);
  ushort_t* W41cl = (ushort_t*)alloc((size_t)64 * 9 * 128 * 2);

  float* roiB  = (float*)alloc((size_t)NPAIR * 1024 * 4);
  float* WtIh  = (float*)alloc((size_t)INSZ * 1024 * 4);
  float* WtHh  = (float*)alloc((size_t)256 * 1024 * 4);
  float* WtDih = (float*)alloc((size_t)KDEC * 1024 * 4);
  float* WtDhh = (float*)alloc((size_t)256 * 1024 * 4);
  float* Gx    = (float*)alloc((size_t)10 * 16 * 1024 * 4);
  float* hall  = (float*)alloc((size_t)10 * 16 * 256 * 4);
  float* cb0   = (float*)alloc((size_t)16 * 256 * 4);
  float* cb1   = (float*)alloc((size_t)16 * 256 * 4);
  float* xt    = (float*)alloc((size_t)16 * KDEC * 4);
  float* hdec  = (float*)alloc((size_t)16 * 256 * 4);

  // ---- LSTM weight transposes (unchanged) ----
  transpose_kernel<<<dim3((1030 + 31) / 32, 32), 256, 0, stream>>>(eWih, WtIh, 1024, 1030);
  transpose_kernel<<<dim3(8, 32), 256, 0, stream>>>(eWhh, WtHh, 1024, 256);
  transpose_kernel<<<dim3((1286 + 31) / 32, 32), 256, 0, stream>>>(dWih, WtDih, 1024, 1286);
  transpose_kernel<<<dim3(8, 32), 256, 0, stream>>>(dWhh, WtDhh, 1024, 256);

  // ---- conv weight reorder to bf16 channels-last ----
  wreorder_kernel<81, 96><<<128, 256, 0, stream>>>(c31w, W31cl);
  wreorder_kernel<128, 128><<<128, 256, 0, stream>>>(c4w, W4cl);
  wreorder_kernel<128, 128><<<64, 256, 0, stream>>>(c41w, W41cl);

  // ---- features to bf16 channels-last ----
  feat_to_bf16cl<<<dim3(32, 8, NFRM), 256, 0, stream>>>(feat, featT);

  // ---- correlation (MFMA banded Gram) ----
  zero_kernel<<<2048, 256, 0, stream>>>((uint4*)corr_cl, corr_bytes / 16);
  corr_mfma_kernel<<<dim3(NPAIR, HFc), 192, 0, stream>>>(featT, corr_cl);

  // ---- convs (MFMA implicit GEMM) ----
  conv_mfma_kernel<96, 128><<<dim3(NPAIR, 21), 256, 0, stream>>>(corr_cl, W31cl, c31b, c3_cl);
  conv_mfma_kernel<128, 128><<<dim3(NPAIR, 21), 256, 0, stream>>>(c3_cl, W4cl, c4b, c4_cl);
  conv_mfma_kernel<128, 64><<<dim3(NPAIR, 21), 256, 0, stream>>>(c4_cl, W41cl, c41b, c41_cl);

  // ---- roi + LSTM tail (unchanged semantics) ----
  roi_cl_kernel<<<NPAIR, 256, 0, stream>>>(c41_cl, boxes, isz, roiB);

  gx_kernel<<<dim3(10, 4, 2), 256, 0, stream>>>(diffs, roiB, WtIh, ebih, ebhh, Gx);
  float* cbuf[2] = {cb0, cb1};
  for (int t = 0; t < 10; t++) {
    const float* hp = (t == 0) ? hall : hall + (size_t)(t - 1) * 16 * 256;
    const float* cp = cbuf[(t + 1) & 1];
    enc_step_kernel<<<8, 256, 0, stream>>>(hp, cp, WtHh, Gx + (size_t)t * 16 * 1024,
                                           hall + (size_t)t * 16 * 256, cbuf[t & 1],
                                           t == 0 ? 1 : 0);
  }
  attn_kernel<<<16, 256, 0, stream>>>(hall, roiB, attw, attb, xt);
  dec_step_kernel<<<8, 256, 0, stream>>>(xt, hall + (size_t)9 * 16 * 256, WtDih, WtDhh,
                                         dbih, dbhh, hdec);
  final_kernel<<<16, 256, 0, stream>>>(hdec, l1w, l1b, l2w, l2b, (float*)d_out);
}

// Round 6
// 1652.535 us; speedup vs baseline: 2.8371x; 1.4084x over previous
//
#include <hip/hip_runtime.h>
#include <math.h>

#define DEVI __device__ __forceinline__

namespace {

typedef unsigned short ushort_t;
typedef __attribute__((ext_vector_type(8))) short bf16x8;
typedef __attribute__((ext_vector_type(4))) unsigned short ushort4v;
typedef __attribute__((ext_vector_type(4))) float f32x4;

constexpr int NPAIR = 160;
constexpr int NFRM  = 176;
constexpr int HFc   = 24, WFc = 42, HW = HFc * WFc;   // 1008 px
constexpr int PH    = 26, PW = 44, PHW = PH * PW;     // padded spatial 1144
constexpr int INSZ  = 1030;
constexpr int KDEC  = 1286;

DEVI float sigm(float x) { return 1.f / (1.f + expf(-x)); }
DEVI float lrelu(float v) { return v > 0.f ? v : 0.1f * v; }

DEVI ushort_t f2bf(float f) {           // fp32 -> bf16 RNE
  unsigned int u = __float_as_uint(f);
  u = (u + 0x7FFF + ((u >> 16) & 1)) >> 16;
  return (ushort_t)u;
}
DEVI float ldbf(const ushort_t* p) {
  return __uint_as_float(((unsigned int)*p) << 16);
}
// MFMA k-order permutation within a 32-channel chunk.
// stored slot s holds channel invperm32(s); perm32(channel) = slot.
DEVI int perm32(int r) {
  return (r < 16) ? ((r >> 2) * 8 + (r & 3)) : (((r - 16) >> 2) * 8 + 4 + (r & 3));
}
DEVI int invperm32(int s) {
  return (s & 4) ? (16 + (s >> 3) * 4 + (s & 3)) : ((s >> 3) * 4 + (s & 3));
}

// ---------------------------------------------------------------------------
// feat fp32 [frame][256][1008] -> featT bf16 [frame][1008][256 perm] + tail pad
// ---------------------------------------------------------------------------
__global__ __launch_bounds__(256) void feat_to_bf16cl(const float* __restrict__ src,
                                                      ushort_t* __restrict__ dst) {
  int fr = blockIdx.z;
  int p0 = blockIdx.x * 32, c0 = blockIdx.y * 32;
  __shared__ float t[32][33];
  int tx = threadIdx.x % 32, ty = threadIdx.x / 32;
  const float* s = src + (size_t)fr * 256 * HW;
#pragma unroll
  for (int i = 0; i < 32; i += 8) {
    int c = c0 + ty + i, pp = p0 + tx;
    t[ty + i][tx] = (pp < HW) ? s[(size_t)c * HW + pp] : 0.f;
  }
  __syncthreads();
  ushort_t* d = dst + (size_t)fr * HW * 256;
#pragma unroll
  for (int i = 0; i < 32; i += 8) {
    int pp = p0 + ty + i, c = c0 + tx;
    if (pp < HW) d[(size_t)pp * 256 + (c & ~31) + perm32(c & 31)] = f2bf(t[tx][ty + i]);
  }
}

// ---------------------------------------------------------------------------
// weights fp32 [OC][IC][3][3] -> bf16 [oc][kp][ICP perm], zero-padded ic
// ---------------------------------------------------------------------------
template <int IC, int ICP>
__global__ __launch_bounds__(256) void wreorder_kernel(const float* __restrict__ w,
                                                       ushort_t* __restrict__ o) {
  int oc = blockIdx.x;
  for (int idx = threadIdx.x; idx < 9 * ICP; idx += 256) {
    int kp = idx / ICP, s = idx % ICP;
    int ic = (s & ~31) + invperm32(s & 31);
    float v = (ic < IC) ? w[((size_t)oc * IC + ic) * 9 + kp] : 0.f;
    o[(size_t)oc * 9 * ICP + idx] = f2bf(v);
  }
}

__global__ void zero_kernel(uint4* __restrict__ p, size_t n16) {
  uint4 z = {0u, 0u, 0u, 0u};
  for (size_t i = blockIdx.x * 256ull + threadIdx.x; i < n16; i += (size_t)gridDim.x * 256)
    p[i] = z;
}

// ---------------------------------------------------------------------------
// Correlation (banded Gram MFMA). Block (pair, y), 3 waves. Batched loads:
// per dy, both j-tiles' 8 fragments (16 x 16B) loaded before 16 MFMAs.
// Output: corr_cl bf16 [pair][PHW][96 perm], halo/invalid pre-zeroed.
// ---------------------------------------------------------------------------
__global__ __launch_bounds__(192) void corr_mfma_kernel(const ushort_t* __restrict__ featT,
                                                        ushort_t* __restrict__ corr_cl) {
  int kk = blockIdx.x, y = blockIdx.y;
  int g = kk + kk / 10;
  int wid = threadIdx.x >> 6, lane = threadIdx.x & 63;
  int x0 = wid * 16;
  int ln = lane & 15, lh = lane >> 4;
  const ushort_t* f1 = featT + ((size_t)g * HW + y * WFc) * 256 + lh * 8;
  const ushort_t* f2b = featT + (size_t)(g + 1) * HW * 256 + lh * 8;

  bf16x8 af[8];
  {
    const ushort_t* ap = f1 + (size_t)(x0 + ln) * 256;
#pragma unroll
    for (int kc = 0; kc < 8; kc++) af[kc] = *(const bf16x8*)(ap + kc * 32);
  }

  for (int dy = 0; dy < 9; dy++) {
    int y2 = y + dy - 4;
    if (y2 < 0 || y2 >= HFc) continue;
    const ushort_t* f2r = f2b + (size_t)y2 * WFc * 256;
    long jl[2];
    jl[0] = (long)x0 - 4 + ln;
    jl[1] = (long)x0 + 12 + ln;
    bf16x8 bfr[2][8];
#pragma unroll
    for (int jt = 0; jt < 2; jt++) {
      const ushort_t* bp = f2r + jl[jt] * 256;
#pragma unroll
      for (int kc = 0; kc < 8; kc++) bfr[jt][kc] = *(const bf16x8*)(bp + kc * 32);
    }
    f32x4 acc[2] = {{0.f, 0.f, 0.f, 0.f}, {0.f, 0.f, 0.f, 0.f}};
#pragma unroll
    for (int kc = 0; kc < 8; kc++) {
      acc[0] = __builtin_amdgcn_mfma_f32_16x16x32_bf16(af[kc], bfr[0][kc], acc[0], 0, 0, 0);
      acc[1] = __builtin_amdgcn_mfma_f32_16x16x32_bf16(af[kc], bfr[1][kc], acc[1], 0, 0, 0);
    }
#pragma unroll
    for (int jt = 0; jt < 2; jt++) {
#pragma unroll
      for (int q = 0; q < 4; q++) {
        int x = x0 + lh * 4 + q;
        int dx = (int)(jl[jt] - x) + 4;
        if (x < WFc && jl[jt] >= 0 && jl[jt] < WFc && dx >= 0 && dx < 9) {
          float v = lrelu(acc[jt][q] * (1.f / 256.f));
          int ch = dy * 9 + dx;
          corr_cl[((size_t)kk * PHW + (y + 1) * PW + x + 1) * 96 + (ch & ~31) + perm32(ch & 31)] =
              f2bf(v);
        }
      }
    }
  }
}

// ---------------------------------------------------------------------------
// 3x3 conv pad-1 + lrelu, implicit GEMM MFMA, padded channels-last bf16.
// kp-batched loads: per (c0, kp-group of 5/4) issue all A/B 16B loads, then MFMAs.
// ---------------------------------------------------------------------------
template <int ICP, int OC>
__global__ __launch_bounds__(256) void conv_mfma_kernel(const ushort_t* __restrict__ in,
                                                        const ushort_t* __restrict__ wgt,
                                                        const float* __restrict__ bias,
                                                        ushort_t* __restrict__ out) {
  constexpr int MT = (OC == 128) ? 2 : 1;
  int n = blockIdx.x, ntg = blockIdx.y;
  int wid = threadIdx.x >> 6, lane = threadIdx.x & 63;
  int ln = lane & 15, lh = lane >> 4;
  int mt0 = wid * MT;

  f32x4 acc[MT][3];
#pragma unroll
  for (int m = 0; m < MT; m++)
#pragma unroll
    for (int j = 0; j < 3; j++) acc[m][j] = (f32x4){0.f, 0.f, 0.f, 0.f};

  int pp[3];
#pragma unroll
  for (int j = 0; j < 3; j++) {
    int t = (ntg * 3 + j) * 16 + ln;
    pp[j] = (t / WFc + 1) * PW + (t % WFc) + 1;
  }
  const ushort_t* inb = in + (size_t)n * PHW * ICP + lh * 8;
  const ushort_t* wb[MT];
#pragma unroll
  for (int m = 0; m < MT; m++)
    wb[m] = wgt + (size_t)((mt0 + m) * 16 + ln) * 9 * ICP + lh * 8;

  for (int c0 = 0; c0 < ICP; c0 += 32) {
#pragma unroll
    for (int g = 0; g < 2; ++g) {
      bf16x8 af[MT][5];
      bf16x8 bfr[3][5];
#pragma unroll
      for (int kk = 0; kk < 5; ++kk) {
        int kp = g * 5 + kk;
        if (kp < 9) {
#pragma unroll
          for (int m = 0; m < MT; ++m)
            af[m][kk] = *(const bf16x8*)(wb[m] + (size_t)kp * ICP + c0);
          int delta = (kp / 3 - 1) * PW + (kp % 3 - 1);
#pragma unroll
          for (int j = 0; j < 3; ++j)
            bfr[j][kk] = *(const bf16x8*)(inb + (size_t)(pp[j] + delta) * ICP + c0);
        }
      }
#pragma unroll
      for (int kk = 0; kk < 5; ++kk) {
        if (g * 5 + kk < 9) {
#pragma unroll
          for (int m = 0; m < MT; ++m)
#pragma unroll
            for (int j = 0; j < 3; ++j)
              acc[m][j] =
                  __builtin_amdgcn_mfma_f32_16x16x32_bf16(af[m][kk], bfr[j][kk], acc[m][j], 0, 0, 0);
        }
      }
    }
  }

#pragma unroll
  for (int m = 0; m < MT; m++) {
    int ocb = (mt0 + m) * 16 + lh * 4;
    int r = ocb & 31;
    int permstart = (r < 16) ? ((r >> 2) * 8) : (((r - 16) >> 2) * 8 + 4);
    int cpos = (ocb & ~31) + permstart;
#pragma unroll
    for (int j = 0; j < 3; j++) {
      ushort4v pk;
#pragma unroll
      for (int q = 0; q < 4; q++) pk[q] = f2bf(lrelu(acc[m][j][q] + bias[ocb + q]));
      *(ushort4v*)(out + ((size_t)n * PHW + pp[j]) * OC + cpos) = pk;
    }
  }
}

// ---------------------------------------------------------------------------
// ROI align (aligned=False) on padded perm channels-last bf16 [pair][PHW][64].
// ---------------------------------------------------------------------------
DEVI float bilinear_pad(const ushort_t* __restrict__ f, float y, float x) {
  bool valid = (y >= -1.f) && (y <= (float)HFc) && (x >= -1.f) && (x <= (float)WFc);
  if (!valid) return 0.f;
  y = fmaxf(y, 0.f);
  x = fmaxf(x, 0.f);
  int y0 = min((int)floorf(y), HFc - 1);
  int x0 = min((int)floorf(x), WFc - 1);
  int y1 = min(y0 + 1, HFc - 1);
  int x1 = min(x0 + 1, WFc - 1);
  if (y0 >= HFc - 1) y = (float)y0;
  if (x0 >= WFc - 1) x = (float)x0;
  float ly = y - y0, lx = x - x0, hy = 1.f - ly, hx = 1.f - lx;
  return hy * hx * ldbf(f + (size_t)((y0 + 1) * PW + x0 + 1) * 64) +
         hy * lx * ldbf(f + (size_t)((y0 + 1) * PW + x1 + 1) * 64) +
         ly * hx * ldbf(f + (size_t)((y1 + 1) * PW + x0 + 1) * 64) +
         ly * lx * ldbf(f + (size_t)((y1 + 1) * PW + x1 + 1) * 64);
}

__global__ __launch_bounds__(256) void roi_cl_kernel(const ushort_t* __restrict__ feat,
                                                     const float* __restrict__ boxes,
                                                     const int* __restrict__ isz,
                                                     float* __restrict__ out) {
  int k = blockIdx.x;
  int g = k + k / 10;
  float scale = 24.0f / (float)isz[0];
  float x1 = boxes[g * 4 + 0] * scale, y1 = boxes[g * 4 + 1] * scale;
  float x2 = boxes[g * 4 + 2] * scale, y2 = boxes[g * 4 + 3] * scale;
  float bw = fmaxf(x2 - x1, 1.0f) * 0.25f;
  float bh = fmaxf(y2 - y1, 1.0f) * 0.25f;
  int tid = threadIdx.x;
  int c = tid & 63, bq = tid >> 6;
  int pc = (c & ~31) + perm32(c & 31);
  const ushort_t* f = feat + (size_t)k * PHW * 64 + pc;
#pragma unroll
  for (int i = 0; i < 4; i++) {
    int bin = bq * 4 + i;
    int pyb = bin / 4, pxb = bin % 4;
    float s = 0.f;
#pragma unroll
    for (int sy = 0; sy < 2; sy++)
#pragma unroll
      for (int sx = 0; sx < 2; sx++) {
        float yy = y1 + (pyb + (sy + 0.5f) * 0.5f) * bh;
        float xx = x1 + (pxb + (sx + 0.5f) * 0.5f) * bw;
        s += bilinear_pad(f, yy, xx);
      }
    out[(size_t)k * 1024 + c * 16 + pyb * 4 + pxb] = s * 0.25f;
  }
}

// ---------------------------------------------------------------------------
// 32x32 LDS-tiled transpose (LSTM weights, fp32)
// ---------------------------------------------------------------------------
__global__ __launch_bounds__(256) void transpose_kernel(const float* __restrict__ src,
                                                        float* __restrict__ dst, int R, int C) {
  __shared__ float t[32][33];
  int bx = blockIdx.x * 32, by = blockIdx.y * 32;
  int tx = threadIdx.x % 32, ty = threadIdx.x / 32;
  for (int i = 0; i < 32; i += 8) {
    int r = by + ty + i, c = bx + tx;
    t[ty + i][tx] = (r < R && c < C) ? src[(size_t)r * C + c] : 0.f;
  }
  __syncthreads();
  for (int i = 0; i < 32; i += 8) {
    int c = bx + ty + i, r = by + tx;
    if (c < C && r < R) dst[(size_t)c * R + r] = t[tx][ty + i];
  }
}

// ---------------------------------------------------------------------------
// G_x[t][b][oc]
// ---------------------------------------------------------------------------
__global__ __launch_bounds__(256) void gx_kernel(const float* __restrict__ diffs,
                                                 const float* __restrict__ roi,
                                                 const float* __restrict__ Wt,
                                                 const float* __restrict__ bih,
                                                 const float* __restrict__ bhh,
                                                 float* __restrict__ Gx) {
  int t = blockIdx.x, bq = blockIdx.y, och = blockIdx.z;
  int tid = threadIdx.x;
  int oc = och * 512 + tid * 2;
  __shared__ float xs[4][256];
  float acc[2][4] = {{0.f, 0.f, 0.f, 0.f}, {0.f, 0.f, 0.f, 0.f}};

  for (int k0 = 0; k0 < INSZ; k0 += 256) {
    int kc = min(256, INSZ - k0);
    __syncthreads();
    for (int idx = tid; idx < 4 * 256; idx += 256) {
      int bi = idx / 256, kk = idx % 256;
      float v = 0.f;
      int k = k0 + kk;
      if (kk < kc) {
        int b = bq * 4 + bi;
        if (k < 6) v = diffs[(b * 10 + t) * 6 + k];
        else if (t > 0) v = roi[((size_t)(b * 10 + t - 1)) * 1024 + k - 6];
      }
      xs[bi][kk] = v;
    }
    __syncthreads();
    int k4 = kc & ~3;
    for (int kk = 0; kk < k4; kk += 4) {
      const float* wp = Wt + (size_t)(k0 + kk) * 1024 + oc;
      float2 w0 = *(const float2*)(wp);
      float2 w1 = *(const float2*)(wp + 1024);
      float2 w2 = *(const float2*)(wp + 2048);
      float2 w3 = *(const float2*)(wp + 3072);
#pragma unroll
      for (int bi = 0; bi < 4; bi++) {
        float4 xv = *(const float4*)&xs[bi][kk];
        acc[0][bi] += w0.x * xv.x + w1.x * xv.y + w2.x * xv.z + w3.x * xv.w;
        acc[1][bi] += w0.y * xv.x + w1.y * xv.y + w2.y * xv.z + w3.y * xv.w;
      }
    }
    for (int kk = k4; kk < kc; kk++) {
      const float* wp = Wt + (size_t)(k0 + kk) * 1024 + oc;
      float2 wv = *(const float2*)wp;
#pragma unroll
      for (int bi = 0; bi < 4; bi++) {
        float xv = xs[bi][kk];
        acc[0][bi] += wv.x * xv;
        acc[1][bi] += wv.y * xv;
      }
    }
  }
  float b0 = bih[oc] + bhh[oc], b1 = bih[oc + 1] + bhh[oc + 1];
  for (int bi = 0; bi < 4; bi++) {
    int b = bq * 4 + bi;
    float* gp = Gx + ((size_t)t * 16 + b) * 1024 + oc;
    gp[0] = acc[0][bi] + b0;
    gp[1] = acc[1][bi] + b1;
  }
}

// ---------------------------------------------------------------------------
// Encoder LSTM step
// ---------------------------------------------------------------------------
__global__ __launch_bounds__(256) void enc_step_kernel(const float* __restrict__ hprev,
                                                       const float* __restrict__ cprev,
                                                       const float* __restrict__ Wt,
                                                       const float* __restrict__ Gx_t,
                                                       float* __restrict__ hout,
                                                       float* __restrict__ cout, int first) {
  int bg = blockIdx.x;
  int tid = threadIdx.x;
  int oc0 = tid * 4;
  __shared__ float xs[2][256];
  __shared__ float gl[1024][2];
  float acc[4][2] = {{0.f,0.f},{0.f,0.f},{0.f,0.f},{0.f,0.f}};

  for (int idx = tid; idx < 512; idx += 256) {
    int bi = idx / 256, k = idx % 256;
    xs[bi][k] = first ? 0.f : hprev[(bg * 2 + bi) * 256 + k];
  }
  __syncthreads();

  for (int k = 0; k < 256; k += 4) {
    const float* wp = Wt + (size_t)k * 1024 + oc0;
    float4 w0 = *(const float4*)(wp);
    float4 w1 = *(const float4*)(wp + 1024);
    float4 w2 = *(const float4*)(wp + 2048);
    float4 w3 = *(const float4*)(wp + 3072);
#pragma unroll
    for (int bi = 0; bi < 2; bi++) {
      float4 xv = *(const float4*)&xs[bi][k];
      acc[0][bi] += w0.x * xv.x + w1.x * xv.y + w2.x * xv.z + w3.x * xv.w;
      acc[1][bi] += w0.y * xv.x + w1.y * xv.y + w2.y * xv.z + w3.y * xv.w;
      acc[2][bi] += w0.z * xv.x + w1.z * xv.y + w2.z * xv.z + w3.z * xv.w;
      acc[3][bi] += w0.w * xv.x + w1.w * xv.y + w2.w * xv.z + w3.w * xv.w;
    }
  }
#pragma unroll
  for (int o = 0; o < 4; o++)
#pragma unroll
    for (int bi = 0; bi < 2; bi++)
      gl[oc0 + o][bi] = acc[o][bi] + Gx_t[(bg * 2 + bi) * 1024 + oc0 + o];
  __syncthreads();

  int j = tid;
#pragma unroll
  for (int bi = 0; bi < 2; bi++) {
    float ig = gl[j][bi], fg = gl[256 + j][bi], gg = gl[512 + j][bi], og = gl[768 + j][bi];
    float cold = first ? 0.f : cprev[(bg * 2 + bi) * 256 + j];
    float cn = sigm(fg) * cold + sigm(ig) * tanhf(gg);
    float hn = sigm(og) * tanhf(cn);
    cout[(bg * 2 + bi) * 256 + j] = cn;
    hout[(bg * 2 + bi) * 256 + j] = hn;
  }
}

// ---------------------------------------------------------------------------
// Attention + decoder-input assembly
// ---------------------------------------------------------------------------
__global__ __launch_bounds__(256) void attn_kernel(const float* __restrict__ hall,
                                                   const float* __restrict__ roi,
                                                   const float* __restrict__ attw,
                                                   const float* __restrict__ attb,
                                                   float* __restrict__ xt) {
  int b = blockIdx.x;
  int tid = threadIdx.x;
  __shared__ float part[256][10];
  __shared__ float aw[10];
  float p[10];
#pragma unroll
  for (int l = 0; l < 10; l++) p[l] = 0.f;

  for (int k = tid; k < KDEC; k += 256) {
    float xv;
    if (k < 256) {
      xv = hall[((size_t)9 * 16 + b) * 256 + k];
    } else {
      int kk = k - 256;
      if (kk < 4) xv = 0.f;
      else if (kk == 4) xv = 1.f;
      else if (kk == 5) xv = 0.f;
      else xv = roi[((size_t)(b * 10 + 9)) * 1024 + kk - 6];
    }
#pragma unroll
    for (int l = 0; l < 10; l++) p[l] += xv * attw[l * KDEC + k];
  }
#pragma unroll
  for (int l = 0; l < 10; l++) part[tid][l] = p[l];
  __syncthreads();
  for (int s = 128; s > 0; s >>= 1) {
    if (tid < s)
#pragma unroll
      for (int l = 0; l < 10; l++) part[tid][l] += part[tid + s][l];
    __syncthreads();
  }
  if (tid == 0) {
    float m = -1e30f;
    float lg[10];
#pragma unroll
    for (int l = 0; l < 10; l++) { lg[l] = part[0][l] + attb[l]; m = fmaxf(m, lg[l]); }
    float s = 0.f;
#pragma unroll
    for (int l = 0; l < 10; l++) { lg[l] = expf(lg[l] - m); s += lg[l]; }
#pragma unroll
    for (int l = 0; l < 10; l++) aw[l] = lg[l] / s;
  }
  __syncthreads();

  for (int k = tid; k < 1030; k += 256) {
    float xv;
    if (k < 4) xv = 0.f;
    else if (k == 4) xv = 1.f;
    else if (k == 5) xv = 0.f;
    else xv = roi[((size_t)(b * 10 + 9)) * 1024 + k - 6];
    xt[(size_t)b * KDEC + k] = xv;
  }
  {
    int j = tid;
    float s = 0.f;
#pragma unroll
    for (int l = 0; l < 10; l++) s += aw[l] * hall[((size_t)l * 16 + b) * 256 + j];
    xt[(size_t)b * KDEC + 1030 + j] = s;
  }
}

// ---------------------------------------------------------------------------
// Decoder LSTM step (c0 = 0)
// ---------------------------------------------------------------------------
__global__ __launch_bounds__(256) void dec_step_kernel(const float* __restrict__ xt,
                                                       const float* __restrict__ h9,
                                                       const float* __restrict__ Wtx,
                                                       const float* __restrict__ Wth,
                                                       const float* __restrict__ bih,
                                                       const float* __restrict__ bhh,
                                                       float* __restrict__ hout) {
  int bg = blockIdx.x;
  int tid = threadIdx.x;
  int oc0 = tid * 4;
  __shared__ float xs[2][1288];
  __shared__ float hs[2][256];
  __shared__ float gl[1024][2];
  float acc[4][2] = {{0.f,0.f},{0.f,0.f},{0.f,0.f},{0.f,0.f}};

  for (int idx = tid; idx < 2 * KDEC; idx += 256) {
    int bi = idx / KDEC, k = idx % KDEC;
    xs[bi][k] = xt[(size_t)(bg * 2 + bi) * KDEC + k];
  }
  for (int idx = tid; idx < 512; idx += 256) {
    int bi = idx / 256, k = idx % 256;
    hs[bi][k] = h9[(bg * 2 + bi) * 256 + k];
  }
  __syncthreads();

  for (int k = 0; k < 1284; k += 4) {
    const float* wp = Wtx + (size_t)k * 1024 + oc0;
    float4 w0 = *(const float4*)(wp);
    float4 w1 = *(const float4*)(wp + 1024);
    float4 w2 = *(const float4*)(wp + 2048);
    float4 w3 = *(const float4*)(wp + 3072);
#pragma unroll
    for (int bi = 0; bi < 2; bi++) {
      float4 xv = *(const float4*)&xs[bi][k];
      acc[0][bi] += w0.x * xv.x + w1.x * xv.y + w2.x * xv.z + w3.x * xv.w;
      acc[1][bi] += w0.y * xv.x + w1.y * xv.y + w2.y * xv.z + w3.y * xv.w;
      acc[2][bi] += w0.z * xv.x + w1.z * xv.y + w2.z * xv.z + w3.z * xv.w;
      acc[3][bi] += w0.w * xv.x + w1.w * xv.y + w2.w * xv.z + w3.w * xv.w;
    }
  }
  for (int k = 1284; k < KDEC; k++) {
    const float* wp = Wtx + (size_t)k * 1024 + oc0;
    float4 w = *(const float4*)wp;
#pragma unroll
    for (int bi = 0; bi < 2; bi++) {
      float xv = xs[bi][k];
      acc[0][bi] += w.x * xv;
      acc[1][bi] += w.y * xv;
      acc[2][bi] += w.z * xv;
      acc[3][bi] += w.w * xv;
    }
  }
  for (int k = 0; k < 256; k += 4) {
    const float* wp = Wth + (size_t)k * 1024 + oc0;
    float4 w0 = *(const float4*)(wp);
    float4 w1 = *(const float4*)(wp + 1024);
    float4 w2 = *(const float4*)(wp + 2048);
    float4 w3 = *(const float4*)(wp + 3072);
#pragma unroll
    for (int bi = 0; bi < 2; bi++) {
      float4 xv = *(const float4*)&hs[bi][k];
      acc[0][bi] += w0.x * xv.x + w1.x * xv.y + w2.x * xv.z + w3.x * xv.w;
      acc[1][bi] += w0.y * xv.x + w1.y * xv.y + w2.y * xv.z + w3.y * xv.w;
      acc[2][bi] += w0.z * xv.x + w1.z * xv.y + w2.z * xv.z + w3.z * xv.w;
      acc[3][bi] += w0.w * xv.x + w1.w * xv.y + w2.w * xv.z + w3.w * xv.w;
    }
  }
#pragma unroll
  for (int o = 0; o < 4; o++)
#pragma unroll
    for (int bi = 0; bi < 2; bi++)
      gl[oc0 + o][bi] = acc[o][bi] + bih[oc0 + o] + bhh[oc0 + o];
  __syncthreads();

  int j = tid;
#pragma unroll
  for (int bi = 0; bi < 2; bi++) {
    float ig = gl[j][bi], fg = gl[256 + j][bi], gg = gl[512 + j][bi], og = gl[768 + j][bi];
    (void)fg;
    float cn = sigm(ig) * tanhf(gg);
    float hn = sigm(og) * tanhf(cn);
    hout[(bg * 2 + bi) * 256 + j] = hn;
  }
}

// ---------------------------------------------------------------------------
// final MLP
// ---------------------------------------------------------------------------
__global__ __launch_bounds__(256) void final_kernel(const float* __restrict__ hdec,
                                                    const float* __restrict__ l1w,
                                                    const float* __restrict__ l1b,
                                                    const float* __restrict__ l2w,
                                                    const float* __restrict__ l2b,
                                                    float* __restrict__ out) {
  int b = blockIdx.x;
  int tid = threadIdx.x;
  __shared__ float hsm[256];
  __shared__ float y1[256];
  hsm[tid] = hdec[b * 256 + tid];
  __syncthreads();
  float a = l1b[tid];
  for (int k = 0; k < 256; k++) a = fmaf(hsm[k], l1w[(size_t)tid * 256 + k], a);
  y1[tid] = fmaxf(a, 0.f);
  __syncthreads();
  if (tid < 6) {
    float s = l2b[tid];
    for (int k = 0; k < 256; k++) s = fmaf(y1[k], l2w[(size_t)tid * 256 + k], s);
    out[b * 6 + tid] = s;
  }
}

}  // namespace

extern "C" void kernel_launch(void* const* d_in, const int* in_sizes, int n_in,
                              void* d_out, int out_size, void* d_ws, size_t ws_size,
                              hipStream_t stream) {
  const float* diffs = (const float*)d_in[0];
  const float* boxes = (const float*)d_in[2];
  const float* feat  = (const float*)d_in[3];
  const int*   isz   = (const int*)d_in[4];
  const float* c31w  = (const float*)d_in[6];
  const float* c31b  = (const float*)d_in[7];
  const float* c4w   = (const float*)d_in[8];
  const float* c4b   = (const float*)d_in[9];
  const float* c41w  = (const float*)d_in[10];
  const float* c41b  = (const float*)d_in[11];
  const float* eWih  = (const float*)d_in[12];
  const float* eWhh  = (const float*)d_in[13];
  const float* ebih  = (const float*)d_in[14];
  const float* ebhh  = (const float*)d_in[15];
  const float* attw  = (const float*)d_in[16];
  const float* attb  = (const float*)d_in[17];
  const float* dWih  = (const float*)d_in[18];
  const float* dWhh  = (const float*)d_in[19];
  const float* dbih  = (const float*)d_in[20];
  const float* dbhh  = (const float*)d_in[21];
  const float* l1w   = (const float*)d_in[22];
  const float* l1b   = (const float*)d_in[23];
  const float* l2w   = (const float*)d_in[24];
  const float* l2b   = (const float*)d_in[25];

  char* base = (char*)d_ws;
  size_t off = 0;
  auto alloc = [&](size_t bytes) {
    char* p = base + off;
    off = (off + bytes + 255) & ~(size_t)255;
    return p;
  };
  const size_t featT_bytes = ((size_t)NFRM * HW + 64) * 256 * 2;   // 90.9 MB
  const size_t corr_bytes  = (size_t)NPAIR * PHW * 96 * 2;         // 35.1 MB
  const size_t c3_bytes    = (size_t)NPAIR * PHW * 128 * 2;        // 46.9 MB
  const size_t c4_bytes    = c3_bytes;
  const size_t c41_bytes   = (size_t)NPAIR * PHW * 64 * 2;         // 23.4 MB

  char* regA = alloc(featT_bytes);          // featT, later c3 (46.9 < 90.9)
  char* regB = alloc(corr_bytes);           // corr_cl, later c41 (23.4 < 35.1)
  char* regC = alloc(c4_bytes);             // c4
  ushort_t* featT   = (ushort_t*)regA;
  ushort_t* c3_cl   = (ushort_t*)regA;
  ushort_t* corr_cl = (ushort_t*)regB;
  ushort_t* c41_cl  = (ushort_t*)regB;
  ushort_t* c4_cl   = (ushort_t*)regC;

  ushort_t* W31cl = (ushort_t*)alloc((size_t)128 * 9 * 96 * 2);
  ushort_t* W4cl  = (ushort_t*)alloc((size_t)128 * 9 * 128 * 2);
  ushort_t* W41cl = (ushort_t*)alloc((size_t)64 * 9 * 128 * 2);

  float* roiB  = (float*)alloc((size_t)NPAIR * 1024 * 4);
  float* WtIh  = (float*)alloc((size_t)INSZ * 1024 * 4);
  float* WtHh  = (float*)alloc((size_t)256 * 1024 * 4);
  float* WtDih = (float*)alloc((size_t)KDEC * 1024 * 4);
  float* WtDhh = (float*)alloc((size_t)256 * 1024 * 4);
  float* Gx    = (float*)alloc((size_t)10 * 16 * 1024 * 4);
  float* hall  = (float*)alloc((size_t)10 * 16 * 256 * 4);
  float* cb0   = (float*)alloc((size_t)16 * 256 * 4);
  float* cb1   = (float*)alloc((size_t)16 * 256 * 4);
  float* xt    = (float*)alloc((size_t)16 * KDEC * 4);
  float* hdec  = (float*)alloc((size_t)16 * 256 * 4);

  transpose_kernel<<<dim3((1030 + 31) / 32, 32), 256, 0, stream>>>(eWih, WtIh, 1024, 1030);
  transpose_kernel<<<dim3(8, 32), 256, 0, stream>>>(eWhh, WtHh, 1024, 256);
  transpose_kernel<<<dim3((1286 + 31) / 32, 32), 256, 0, stream>>>(dWih, WtDih, 1024, 1286);
  transpose_kernel<<<dim3(8, 32), 256, 0, stream>>>(dWhh, WtDhh, 1024, 256);

  wreorder_kernel<81, 96><<<128, 256, 0, stream>>>(c31w, W31cl);
  wreorder_kernel<128, 128><<<128, 256, 0, stream>>>(c4w, W4cl);
  wreorder_kernel<128, 128><<<64, 256, 0, stream>>>(c41w, W41cl);

  feat_to_bf16cl<<<dim3(32, 8, NFRM), 256, 0, stream>>>(feat, featT);

  // zero corr (halo + unwritten channels) and c4 halo
  zero_kernel<<<2048, 256, 0, stream>>>((uint4*)corr_cl, corr_bytes / 16);
  zero_kernel<<<2048, 256, 0, stream>>>((uint4*)c4_cl, c4_bytes / 16);

  corr_mfma_kernel<<<dim3(NPAIR, HFc), 192, 0, stream>>>(featT, corr_cl);

  // featT dead -> zero c3 region, run conv3_1
  zero_kernel<<<2048, 256, 0, stream>>>((uint4*)c3_cl, c3_bytes / 16);
  conv_mfma_kernel<96, 128><<<dim3(NPAIR, 21), 256, 0, stream>>>(corr_cl, W31cl, c31b, c3_cl);

  // corr dead -> zero c41 region, then conv4 / conv4_1
  zero_kernel<<<2048, 256, 0, stream>>>((uint4*)c41_cl, c41_bytes / 16);
  conv_mfma_kernel<128, 128><<<dim3(NPAIR, 21), 256, 0, stream>>>(c3_cl, W4cl, c4b, c4_cl);
  conv_mfma_kernel<128, 64><<<dim3(NPAIR, 21), 256, 0, stream>>>(c4_cl, W41cl, c41b, c41_cl);

  roi_cl_kernel<<<NPAIR, 256, 0, stream>>>(c41_cl, boxes, isz, roiB);

  gx_kernel<<<dim3(10, 4, 2), 256, 0, stream>>>(diffs, roiB, WtIh, ebih, ebhh, Gx);
  float* cbuf[2] = {cb0, cb1};
  for (int t = 0; t < 10; t++) {
    const float* hp = (t == 0) ? hall : hall + (size_t)(t - 1) * 16 * 256;
    const float* cp = cbuf[(t + 1) & 1];
    enc_step_kernel<<<8, 256, 0, stream>>>(hp, cp, WtHh, Gx + (size_t)t * 16 * 1024,
                                           hall + (size_t)t * 16 * 256, cbuf[t & 1],
                                           t == 0 ? 1 : 0);
  }
  attn_kernel<<<16, 256, 0, stream>>>(hall, roiB, attw, attb, xt);
  dec_step_kernel<<<8, 256, 0, stream>>>(xt, hall + (size_t)9 * 16 * 256, WtDih, WtDhh,
                                         dbih, dbhh, hdec);
  final_kernel<<<16, 256, 0, stream>>>(hdec, l1w, l1b, l2w, l2b, (float*)d_out);
}